// Round 11
// baseline (462.104 us; speedup 1.0000x reference)
//
#include <hip/hip_runtime.h>
#include <hip/hip_fp16.h>

// ---------------------------------------------------------------------------
// GCN 3-layer forward. Gather-based CSR aggregation with f16 gather payloads.
// CSR build: count -> scan -> TWO-PHASE fill:
//   Phase A (k_bucket): bin edges into 8 dst-range buckets via LDS staging,
//     flushed as contiguous chunks (coalesced writes, no scatter).
//   Phase B (k_fillB): per-range (XCD-pinned) compact scatter; working set
//     (0.8 MB bucket + 0.8 MB CSR slice + cursors) is L2-resident, so 4B
//     scattered writes combine into full lines.
// No nontemporal hints anywhere (R10: they defeat useful L2 reuse on gfx950).
//
// d_ws (4-byte units):
//   csr  [E]     packed uint (src<<16 | f16(norm)), grouped by dst
//   tmp  [E]     packed uint (cLocal<<16 | src), grouped by dst-range
//   Ah   [N*64]  post-GEMM h as f16 (128 halves/row)
//   B    [N*128] layer output f32
//   Ch   [N*8]   layer-3 post-GEMM as f16
//   dinv [N]
//   offs [N+1]
//   cnt  [N]
//   cur  [N]     fill cursor (init = offs)
//   bsum [256]
//   gcur [8]     per-range bucket append cursor (init = offs[g*rs])
// ---------------------------------------------------------------------------

static inline int cdiv(int a, int b) { return (a + b - 1) / b; }

__global__ __launch_bounds__(256) void k_zero_int(int* p, int n) {
    int i = blockIdx.x * 256 + threadIdx.x;
    if (i < n) p[i] = 0;
}

__global__ __launch_bounds__(256) void k_count(const int* __restrict__ col, int* cnt, int e) {
    int i = blockIdx.x * 256 + threadIdx.x;
    if (i < e) atomicAdd(&cnt[col[i]], 1);
}

// per-256-chunk sums for scan; also computes dinv = rsqrt(deg+1)
__global__ __launch_bounds__(256) void k_scanA(const int* __restrict__ cnt, int* bsum,
                                               float* __restrict__ dinv, int n) {
    __shared__ int s[256];
    int t = threadIdx.x;
    int i = blockIdx.x * 256 + t;
    int v = (i < n) ? cnt[i] : 0;
    if (i < n) dinv[i] = rsqrtf((float)(v + 1));
    s[t] = v;
    __syncthreads();
    for (int off = 128; off > 0; off >>= 1) {
        if (t < off) s[t] += s[t + off];
        __syncthreads();
    }
    if (t == 0) bsum[blockIdx.x] = s[0];
}

__global__ __launch_bounds__(256) void k_scanB(int* bsum, int nb) {
    __shared__ int s[256];
    int t = threadIdx.x;
    int v = (t < nb) ? bsum[t] : 0;
    s[t] = v;
    for (int off = 1; off < 256; off <<= 1) {
        __syncthreads();
        int x = (t >= off) ? s[t - off] : 0;
        __syncthreads();
        s[t] += x;
    }
    __syncthreads();
    if (t < nb) bsum[t] = s[t] - v;
}

// exclusive scan -> offs; cursor copy; per-range bucket cursors gcur
__global__ __launch_bounds__(256) void k_scanC(const int* __restrict__ cnt, const int* __restrict__ bsum,
                                               int* offs, int* cur, int* gcur, int rs, int n) {
    __shared__ int s[256];
    int t = threadIdx.x;
    int i = blockIdx.x * 256 + t;
    int v = (i < n) ? cnt[i] : 0;
    s[t] = v;
    for (int off = 1; off < 256; off <<= 1) {
        __syncthreads();
        int x = (t >= off) ? s[t - off] : 0;
        __syncthreads();
        s[t] += x;
    }
    __syncthreads();
    int ov = bsum[blockIdx.x] + s[t] - v;
    if (i <= n) offs[i] = ov;
    if (i < n) {
        cur[i] = ov;
        if ((i % rs) == 0) gcur[i / rs] = ov;
    }
}

// Phase A: bin edges into 8 dst-range buckets. LDS staging, chunked
// coalesced flushes into tmp[] (range region = CSR region order).
__global__ __launch_bounds__(256) void k_bucket(const int* __restrict__ row, const int* __restrict__ col,
                                                int* gcur, unsigned int* __restrict__ tmp,
                                                int e, int rs, int nblk) {
    __shared__ unsigned int buf[8][512];
    __shared__ int bcnt[8];
    __shared__ int bbase[8];
    int tid = threadIdx.x;
    if (tid < 8) bcnt[tid] = 0;
    __syncthreads();
    int stride = nblk * 256;
    for (int base = blockIdx.x * 256; base < e; base += stride) {
        int i = base + tid;
        if (i < e) {
            int c = col[i], r = row[i];
            int g = c / rs;
            int slot = atomicAdd(&bcnt[g], 1);
            buf[g][slot] = ((unsigned int)(c - g * rs) << 16) | (unsigned int)r;
        }
        __syncthreads();
        #pragma unroll
        for (int g = 0; g < 8; ++g) {
            int c8 = bcnt[g];                 // uniform read post-barrier
            if (c8 >= 256) {                  // uniform branch
                if (tid == 0) bbase[g] = atomicAdd(&gcur[g], c8);
                __syncthreads();
                int gb = bbase[g];
                for (int k = tid; k < c8; k += 256)
                    tmp[gb + k] = buf[g][k];
                __syncthreads();
                if (tid == 0) bcnt[g] = 0;
                __syncthreads();
            }
        }
        __syncthreads();                      // appends of next batch wait for flush reads
    }
    // final flush (uniform: bcnt reads after barrier, conditions uniform)
    #pragma unroll
    for (int g = 0; g < 8; ++g) {
        int c8 = bcnt[g];
        if (c8 > 0) {
            if (tid == 0) bbase[g] = atomicAdd(&gcur[g], c8);
            __syncthreads();
            int gb = bbase[g];
            for (int k = tid; k < c8; k += 256)
                tmp[gb + k] = buf[g][k];
            __syncthreads();
        }
    }
}

// Phase B: per-range compact scatter. g = blockIdx&7 (XCD pin); reads the
// range's contiguous tmp slice, scatters into its L2-resident CSR slice.
__global__ __launch_bounds__(256) void k_fillB(const unsigned int* __restrict__ tmp,
                                               const float* __restrict__ dinv,
                                               const int* __restrict__ offs, int* cur,
                                               unsigned int* __restrict__ csr,
                                               int n, int rs, int nblk) {
    int g = blockIdx.x & 7;
    int b = blockIdx.x >> 3;
    int base = g * rs;
    int en = min(base + rs, n);
    int s0 = offs[base], s1 = offs[en];
    int stride = nblk * 256;
    for (int i = s0 + b * 256 + threadIdx.x; i < s1; i += stride) {
        unsigned int u = tmp[i];
        int r = (int)(u & 0xffffu);
        int c = base + (int)(u >> 16);
        float w = dinv[r] * dinv[c];
        int pos = atomicAdd(&cur[c], 1);
        csr[pos] = ((unsigned int)r << 16) |
                   (unsigned int)__half_as_ushort(__float2half_rn(w));
    }
}

// Ah[n,128](f16) = X[n,128](f32) @ W[128,128]. 128-row tile, 8x8 micro-tile.
__global__ __launch_bounds__(256) void k_gemm128(const float* __restrict__ X, const float* __restrict__ W,
                                                 __half* __restrict__ Ah, int n) {
    __shared__ float sW[128 * 128];
    __shared__ float sX[16][128];
    int tid = threadIdx.x;
    for (int i = tid; i < 4096; i += 256)
        ((float4*)sW)[i] = ((const float4*)W)[i];

    int row0 = blockIdx.x * 128;
    int tx = tid & 15, ty = tid >> 4;
    float acc[8][8];
    #pragma unroll
    for (int i = 0; i < 8; ++i)
        #pragma unroll
        for (int j = 0; j < 8; ++j) acc[i][j] = 0.f;

    for (int k0 = 0; k0 < 128; k0 += 16) {
        __syncthreads();
        #pragma unroll
        for (int i = tid; i < 512; i += 256) {
            int r = i >> 2, kq = i & 3;
            int gr = row0 + r;
            float4 v = (gr < n) ? ((const float4*)X)[(size_t)gr * 32 + (k0 >> 2) + kq]
                                : make_float4(0.f, 0.f, 0.f, 0.f);
            sX[kq * 4 + 0][r] = v.x;
            sX[kq * 4 + 1][r] = v.y;
            sX[kq * 4 + 2][r] = v.z;
            sX[kq * 4 + 3][r] = v.w;
        }
        __syncthreads();
        #pragma unroll
        for (int kk = 0; kk < 16; ++kk) {
            float a[8], b[8];
            *(float4*)&a[0] = *(const float4*)&sX[kk][ty * 8];
            *(float4*)&a[4] = *(const float4*)&sX[kk][ty * 8 + 4];
            *(float4*)&b[0] = *(const float4*)&sW[(k0 + kk) * 128 + tx * 8];
            *(float4*)&b[4] = *(const float4*)&sW[(k0 + kk) * 128 + tx * 8 + 4];
            #pragma unroll
            for (int i = 0; i < 8; ++i)
                #pragma unroll
                for (int j = 0; j < 8; ++j)
                    acc[i][j] = fmaf(a[i], b[j], acc[i][j]);
        }
    }
    #pragma unroll
    for (int i = 0; i < 8; ++i) {
        int gr = row0 + ty * 8 + i;
        if (gr < n) {
            union { uint4 u; __half2 h[4]; } pk;
            pk.h[0] = __floats2half2_rn(acc[i][0], acc[i][1]);
            pk.h[1] = __floats2half2_rn(acc[i][2], acc[i][3]);
            pk.h[2] = __floats2half2_rn(acc[i][4], acc[i][5]);
            pk.h[3] = __floats2half2_rn(acc[i][6], acc[i][7]);
            ((uint4*)Ah)[(size_t)gr * 16 + tx] = pk.u;   // cols tx*8..+7
        }
    }
}

// Ch[n,16](f16) = X[n,128](f32) @ W[128,16].
__global__ __launch_bounds__(256) void k_gemm16(const float* __restrict__ X, const float* __restrict__ W,
                                                __half* __restrict__ Ch, int n) {
    __shared__ float sX[16 * 132];
    __shared__ float sW[128 * 16];
    int tid = threadIdx.x;
    for (int i = tid; i < 512; i += 256)
        ((float4*)sW)[i] = ((const float4*)W)[i];
    int row0 = blockIdx.x * 16;
    for (int i = tid; i < 512; i += 256) {
        int r = i >> 5, c = i & 31;
        int gr = row0 + r;
        float4 v = (gr < n) ? ((const float4*)X)[(size_t)gr * 32 + c]
                            : make_float4(0.f, 0.f, 0.f, 0.f);
        *(float4*)&sX[r * 132 + c * 4] = v;
    }
    __syncthreads();

    int rl = tid >> 4, cj = tid & 15;
    float acc = 0.f;
    #pragma unroll 8
    for (int k = 0; k < 128; ++k)
        acc = fmaf(sX[rl * 132 + k], sW[k * 16 + cj], acc);
    int gr = row0 + rl;
    if (gr < n) Ch[(size_t)gr * 16 + cj] = __float2half_rn(acc);
}

// F=128 gather-aggregate from f16 H: wave per node, 4 halves (8B)/lane,
// even/odd edge halves, 4-way unroll (8 edges in flight). f32 accumulate.
__global__ __launch_bounds__(256) void k_agg128(const __half* __restrict__ Hh, const unsigned int* __restrict__ csr,
                                                const int* __restrict__ offs, const float* __restrict__ dinv,
                                                const float* __restrict__ b, float* __restrict__ out, int n) {
    int node = (blockIdx.x * 256 + threadIdx.x) >> 6;
    if (node >= n) return;
    int lane = threadIdx.x & 63;
    int sub  = lane & 31;     // uint2 (4 halves) within the 128-f row
    int half = lane >> 5;     // 0: even edges, 1: odd edges
    const uint2* H2 = (const uint2*)Hh;   // row stride = 32 uint2
    int ed = offs[node], end = offs[node + 1];
    float4 acc = make_float4(0.f, 0.f, 0.f, 0.f);

    #define EDGE_FMA(P)                                                          \
        {                                                                        \
            uint2 q = H2[(size_t)((P) >> 16) * 32 + sub];                        \
            float w = __half2float(__ushort_as_half((unsigned short)((P) & 0xffffu))); \
            float2 f01 = __half22float2(*(const __half2*)&q.x);                  \
            float2 f23 = __half22float2(*(const __half2*)&q.y);                  \
            acc.x = fmaf(w, f01.x, acc.x); acc.y = fmaf(w, f01.y, acc.y);        \
            acc.z = fmaf(w, f23.x, acc.z); acc.w = fmaf(w, f23.y, acc.w);        \
        }

    for (; ed + 7 < end; ed += 8) {
        unsigned int p0 = csr[ed     + half];
        unsigned int p1 = csr[ed + 2 + half];
        unsigned int p2 = csr[ed + 4 + half];
        unsigned int p3 = csr[ed + 6 + half];
        EDGE_FMA(p0); EDGE_FMA(p1); EDGE_FMA(p2); EDGE_FMA(p3);
    }
    #pragma unroll
    for (int s = 0; s < 4; ++s) {          // tail: up to 7 edges
        int idx = ed + 2 * s + half;
        if (idx < end) {
            unsigned int p = csr[idx];
            EDGE_FMA(p);
        }
    }
    #undef EDGE_FMA

    acc.x += __shfl_xor(acc.x, 32);
    acc.y += __shfl_xor(acc.y, 32);
    acc.z += __shfl_xor(acc.z, 32);
    acc.w += __shfl_xor(acc.w, 32);

    float di = dinv[node], sl = di * di;
    uint2 qh = H2[(size_t)node * 32 + sub];
    float2 h01 = __half22float2(*(const __half2*)&qh.x);
    float2 h23 = __half22float2(*(const __half2*)&qh.y);
    float4 bv = ((const float4*)b)[sub];
    float4 o;
    o.x = fmaxf(fmaf(sl, h01.x, acc.x) + bv.x, 0.f);
    o.y = fmaxf(fmaf(sl, h01.y, acc.y) + bv.y, 0.f);
    o.z = fmaxf(fmaf(sl, h23.x, acc.z) + bv.z, 0.f);
    o.w = fmaxf(fmaf(sl, h23.y, acc.w) + bv.w, 0.f);
    if (half == 0)
        ((float4*)out)[(size_t)node * 32 + sub] = o;
}

// F=16 gather-aggregate from f16 C: 8 lanes/node (4 x uint2, even/odd halves).
__global__ __launch_bounds__(256) void k_agg16(const __half* __restrict__ Ch, const unsigned int* __restrict__ csr,
                                               const int* __restrict__ offs, const float* __restrict__ dinv,
                                               const float* __restrict__ b, float* __restrict__ out, int n) {
    int t = blockIdx.x * 256 + threadIdx.x;
    int node = t >> 3;
    if (node >= n) return;
    int lane = t & 7;
    int sub  = lane & 3;      // uint2 (4 halves) within the 16-f row
    int half = lane >> 2;
    const uint2* C2 = (const uint2*)Ch;   // row stride = 4 uint2
    int ed = offs[node], end = offs[node + 1];
    float4 acc = make_float4(0.f, 0.f, 0.f, 0.f);

    #define EDGE_FMA16(P)                                                        \
        {                                                                        \
            uint2 q = C2[(size_t)((P) >> 16) * 4 + sub];                         \
            float w = __half2float(__ushort_as_half((unsigned short)((P) & 0xffffu))); \
            float2 f01 = __half22float2(*(const __half2*)&q.x);                  \
            float2 f23 = __half22float2(*(const __half2*)&q.y);                  \
            acc.x = fmaf(w, f01.x, acc.x); acc.y = fmaf(w, f01.y, acc.y);        \
            acc.z = fmaf(w, f23.x, acc.z); acc.w = fmaf(w, f23.y, acc.w);        \
        }

    for (; ed + 3 < end; ed += 4) {
        unsigned int p0 = csr[ed     + half];
        unsigned int p1 = csr[ed + 2 + half];
        EDGE_FMA16(p0); EDGE_FMA16(p1);
    }
    #pragma unroll
    for (int s = 0; s < 2; ++s) {          // tail: up to 3 edges
        int idx = ed + 2 * s + half;
        if (idx < end) {
            unsigned int p = csr[idx];
            EDGE_FMA16(p);
        }
    }
    #undef EDGE_FMA16

    acc.x += __shfl_xor(acc.x, 4);
    acc.y += __shfl_xor(acc.y, 4);
    acc.z += __shfl_xor(acc.z, 4);
    acc.w += __shfl_xor(acc.w, 4);

    float di = dinv[node], sl = di * di;
    uint2 qh = C2[(size_t)node * 4 + sub];
    float2 h01 = __half22float2(*(const __half2*)&qh.x);
    float2 h23 = __half22float2(*(const __half2*)&qh.y);
    float4 bv = ((const float4*)b)[sub];
    float4 o;
    o.x = fmaxf(fmaf(sl, h01.x, acc.x) + bv.x, 0.f);
    o.y = fmaxf(fmaf(sl, h01.y, acc.y) + bv.y, 0.f);
    o.z = fmaxf(fmaf(sl, h23.x, acc.z) + bv.z, 0.f);
    o.w = fmaxf(fmaf(sl, h23.y, acc.w) + bv.w, 0.f);
    if (half == 0)
        ((float4*)out)[(size_t)node * 4 + sub] = o;
}

extern "C" void kernel_launch(void* const* d_in, const int* in_sizes, int n_in,
                              void* d_out, int out_size, void* d_ws, size_t ws_size,
                              hipStream_t stream) {
    const float* x  = (const float*)d_in[0];
    const int*   ei = (const int*)d_in[1];
    const float* W1 = (const float*)d_in[2];
    const float* b1 = (const float*)d_in[3];
    const float* W2 = (const float*)d_in[4];
    const float* b2 = (const float*)d_in[5];
    const float* W3 = (const float*)d_in[6];
    const float* b3 = (const float*)d_in[7];

    const int n = in_sizes[0] / 128;   // 50000 (< 65536, required by packed formats)
    const int e = in_sizes[1] / 2;
    const int* row = ei;       // source j
    const int* col = ei + e;   // target i
    const int rs = (n + 7) >> 3;

    unsigned int* csr = (unsigned int*)d_ws;
    unsigned int* tmp = csr + e;
    __half* Ah  = (__half*)(tmp + e);
    float*  B   = (float*)(Ah + (size_t)n * 128);
    __half* Ch  = (__half*)(B + (size_t)n * 128);
    float* dinv = (float*)(Ch + (size_t)n * 16);
    int*   offs = (int*)(dinv + n);
    int*   cnt  = offs + (n + 1);
    int*   cur  = cnt + n;
    int*   bsum = cur + n;
    int*   gcur = bsum + 256;
    float* out  = (float*)d_out;

    const int nb = cdiv(n + 1, 256);
    const int bucketBlocks = 1024;
    const int fillBBlocks  = 128;      // per range; grid = 8*128

    // --- CSR build ---
    k_zero_int<<<cdiv(n, 256), 256, 0, stream>>>(cnt, n);
    k_count   <<<cdiv(e, 256), 256, 0, stream>>>(col, cnt, e);
    k_scanA   <<<nb, 256, 0, stream>>>(cnt, bsum, dinv, n);
    k_scanB   <<<1, 256, 0, stream>>>(bsum, nb);
    k_scanC   <<<nb, 256, 0, stream>>>(cnt, bsum, offs, cur, gcur, rs, n);
    k_bucket  <<<bucketBlocks, 256, 0, stream>>>(row, col, gcur, tmp, e, rs, bucketBlocks);
    k_fillB   <<<8 * fillBBlocks, 256, 0, stream>>>(tmp, dinv, offs, cur, csr, n, rs, fillBBlocks);

    // --- layer 1 ---
    k_gemm128<<<cdiv(n, 128), 256, 0, stream>>>(x, W1, Ah, n);
    k_agg128 <<<cdiv(n * 64, 256), 256, 0, stream>>>(Ah, csr, offs, dinv, b1, B, n);
    // --- layer 2 ---
    k_gemm128<<<cdiv(n, 128), 256, 0, stream>>>(B, W2, Ah, n);
    k_agg128 <<<cdiv(n * 64, 256), 256, 0, stream>>>(Ah, csr, offs, dinv, b2, B, n);
    // --- layer 3 ---
    k_gemm16 <<<cdiv(n, 16), 256, 0, stream>>>(B, W3, Ch, n);
    k_agg16  <<<cdiv(n * 8, 256), 256, 0, stream>>>(Ch, csr, offs, dinv, b3, out, n);
}

// Round 12
// 365.086 us; speedup vs baseline: 1.2657x; 1.2657x over previous
//
#include <hip/hip_runtime.h>
#include <hip/hip_fp16.h>

// ---------------------------------------------------------------------------
// GCN 3-layer forward.
// Key refactor: agg[i] = dinv[i] * ( sum_e h'[src_e] + h'[i] ),  h' = dinv*h
// folded into the GEMM epilogue. So CSR = 2-byte src id only (3.2 MB),
// agg inner loop = gather + add (no weight), fill does no dinv gathers.
// Fill is XCD-partitioned (8 dst ranges, blockIdx&7), plain loads (no NT).
//
// d_ws (4-byte units):
//   csr  [E/2]   ushort src ids, grouped by dst
//   Ah   [N*64]  post-GEMM h' as f16 (128 halves/row)
//   B    [N*128] layer output f32
//   Ch   [N*8]   layer-3 post-GEMM h' as f16
//   dinv [N]
//   offs [N+1]
//   cnt  [N]
//   cur  [N]     fill cursor (init = offs)
//   bsum [256]
// ---------------------------------------------------------------------------

static inline int cdiv(int a, int b) { return (a + b - 1) / b; }

__global__ __launch_bounds__(256) void k_zero_int(int* p, int n) {
    int i = blockIdx.x * 256 + threadIdx.x;
    if (i < n) p[i] = 0;
}

__global__ __launch_bounds__(256) void k_count(const int* __restrict__ col, int* cnt, int e) {
    int i = blockIdx.x * 256 + threadIdx.x;
    if (i < e) atomicAdd(&cnt[col[i]], 1);
}

// per-256-chunk sums for scan; also computes dinv = rsqrt(deg+1)
__global__ __launch_bounds__(256) void k_scanA(const int* __restrict__ cnt, int* bsum,
                                               float* __restrict__ dinv, int n) {
    __shared__ int s[256];
    int t = threadIdx.x;
    int i = blockIdx.x * 256 + t;
    int v = (i < n) ? cnt[i] : 0;
    if (i < n) dinv[i] = rsqrtf((float)(v + 1));
    s[t] = v;
    __syncthreads();
    for (int off = 128; off > 0; off >>= 1) {
        if (t < off) s[t] += s[t + off];
        __syncthreads();
    }
    if (t == 0) bsum[blockIdx.x] = s[0];
}

__global__ __launch_bounds__(256) void k_scanB(int* bsum, int nb) {
    __shared__ int s[256];
    int t = threadIdx.x;
    int v = (t < nb) ? bsum[t] : 0;
    s[t] = v;
    for (int off = 1; off < 256; off <<= 1) {
        __syncthreads();
        int x = (t >= off) ? s[t - off] : 0;
        __syncthreads();
        s[t] += x;
    }
    __syncthreads();
    if (t < nb) bsum[t] = s[t] - v;
}

// per-chunk exclusive scan + block offset -> offs; cursor copy for fill
__global__ __launch_bounds__(256) void k_scanC(const int* __restrict__ cnt, const int* __restrict__ bsum,
                                               int* offs, int* cur, int n) {
    __shared__ int s[256];
    int t = threadIdx.x;
    int i = blockIdx.x * 256 + t;
    int v = (i < n) ? cnt[i] : 0;
    s[t] = v;
    for (int off = 1; off < 256; off <<= 1) {
        __syncthreads();
        int x = (t >= off) ? s[t - off] : 0;
        __syncthreads();
        s[t] += x;
    }
    __syncthreads();
    int ov = bsum[blockIdx.x] + s[t] - v;
    if (i <= n) offs[i] = ov;
    if (i < n) cur[i] = ov;
}

// XCD-partitioned fill: range g = blockIdx&7 owns dst in [g*rs, g*rs+rs).
// CSR entry is just the 16-bit src id.
__global__ __launch_bounds__(256) void k_fill_xcd(const int* __restrict__ row, const int* __restrict__ col,
                                                  int* cur, unsigned short* __restrict__ csr,
                                                  int e, int n, int nblk) {
    int g = blockIdx.x & 7;
    int b = blockIdx.x >> 3;
    int rs = (n + 7) >> 3;
    int lo = g * rs;
    int hi = min(lo + rs, n);
    int stride = nblk * 256;
    for (int i = b * 256 + threadIdx.x; i < e; i += stride) {
        int c = col[i];
        if (c >= lo && c < hi) {
            int pos = atomicAdd(&cur[c], 1);
            csr[pos] = (unsigned short)row[i];
        }
    }
}

// Ah[n,128](f16) = dinv[row] * (X[n,128](f32) @ W[128,128]).
__global__ __launch_bounds__(256) void k_gemm128(const float* __restrict__ X, const float* __restrict__ W,
                                                 const float* __restrict__ dinv,
                                                 __half* __restrict__ Ah, int n) {
    __shared__ float sW[128 * 128];
    __shared__ float sX[16][128];
    int tid = threadIdx.x;
    for (int i = tid; i < 4096; i += 256)
        ((float4*)sW)[i] = ((const float4*)W)[i];

    int row0 = blockIdx.x * 128;
    int tx = tid & 15, ty = tid >> 4;
    float acc[8][8];
    #pragma unroll
    for (int i = 0; i < 8; ++i)
        #pragma unroll
        for (int j = 0; j < 8; ++j) acc[i][j] = 0.f;

    for (int k0 = 0; k0 < 128; k0 += 16) {
        __syncthreads();
        #pragma unroll
        for (int i = tid; i < 512; i += 256) {
            int r = i >> 2, kq = i & 3;
            int gr = row0 + r;
            float4 v = (gr < n) ? ((const float4*)X)[(size_t)gr * 32 + (k0 >> 2) + kq]
                                : make_float4(0.f, 0.f, 0.f, 0.f);
            sX[kq * 4 + 0][r] = v.x;
            sX[kq * 4 + 1][r] = v.y;
            sX[kq * 4 + 2][r] = v.z;
            sX[kq * 4 + 3][r] = v.w;
        }
        __syncthreads();
        #pragma unroll
        for (int kk = 0; kk < 16; ++kk) {
            float a[8], b[8];
            *(float4*)&a[0] = *(const float4*)&sX[kk][ty * 8];
            *(float4*)&a[4] = *(const float4*)&sX[kk][ty * 8 + 4];
            *(float4*)&b[0] = *(const float4*)&sW[(k0 + kk) * 128 + tx * 8];
            *(float4*)&b[4] = *(const float4*)&sW[(k0 + kk) * 128 + tx * 8 + 4];
            #pragma unroll
            for (int i = 0; i < 8; ++i)
                #pragma unroll
                for (int j = 0; j < 8; ++j)
                    acc[i][j] = fmaf(a[i], b[j], acc[i][j]);
        }
    }
    #pragma unroll
    for (int i = 0; i < 8; ++i) {
        int gr = row0 + ty * 8 + i;
        if (gr < n) {
            float di = dinv[gr];
            union { uint4 u; __half2 h[4]; } pk;
            pk.h[0] = __floats2half2_rn(di * acc[i][0], di * acc[i][1]);
            pk.h[1] = __floats2half2_rn(di * acc[i][2], di * acc[i][3]);
            pk.h[2] = __floats2half2_rn(di * acc[i][4], di * acc[i][5]);
            pk.h[3] = __floats2half2_rn(di * acc[i][6], di * acc[i][7]);
            ((uint4*)Ah)[(size_t)gr * 16 + tx] = pk.u;   // cols tx*8..+7
        }
    }
}

// Ch[n,16](f16) = dinv[row] * (X[n,128](f32) @ W[128,16]).
__global__ __launch_bounds__(256) void k_gemm16(const float* __restrict__ X, const float* __restrict__ W,
                                                const float* __restrict__ dinv,
                                                __half* __restrict__ Ch, int n) {
    __shared__ float sX[16 * 132];
    __shared__ float sW[128 * 16];
    int tid = threadIdx.x;
    for (int i = tid; i < 512; i += 256)
        ((float4*)sW)[i] = ((const float4*)W)[i];
    int row0 = blockIdx.x * 16;
    for (int i = tid; i < 512; i += 256) {
        int r = i >> 5, c = i & 31;
        int gr = row0 + r;
        float4 v = (gr < n) ? ((const float4*)X)[(size_t)gr * 32 + c]
                            : make_float4(0.f, 0.f, 0.f, 0.f);
        *(float4*)&sX[r * 132 + c * 4] = v;
    }
    __syncthreads();

    int rl = tid >> 4, cj = tid & 15;
    float acc = 0.f;
    #pragma unroll 8
    for (int k = 0; k < 128; ++k)
        acc = fmaf(sX[rl * 132 + k], sW[k * 16 + cj], acc);
    int gr = row0 + rl;
    if (gr < n) Ch[(size_t)gr * 16 + cj] = __float2half_rn(dinv[gr] * acc);
}

// F=128 gather-aggregate from f16 h': wave per node, 4 halves (8B)/lane,
// even/odd edge halves, 4-way unroll (8 edges in flight). No per-edge weight.
// out[i] = relu( dinv[i] * (sum_e h'[src_e] + h'[i]) + b )
__global__ __launch_bounds__(256) void k_agg128(const __half* __restrict__ Hh, const unsigned short* __restrict__ csr,
                                                const int* __restrict__ offs, const float* __restrict__ dinv,
                                                const float* __restrict__ b, float* __restrict__ out, int n) {
    int node = (blockIdx.x * 256 + threadIdx.x) >> 6;
    if (node >= n) return;
    int lane = threadIdx.x & 63;
    int sub  = lane & 31;     // uint2 (4 halves) within the 128-f row
    int half = lane >> 5;     // 0: even edges, 1: odd edges
    const uint2* H2 = (const uint2*)Hh;   // row stride = 32 uint2
    int ed = offs[node], end = offs[node + 1];
    float4 acc = make_float4(0.f, 0.f, 0.f, 0.f);

    #define EDGE_ADD(R)                                                          \
        {                                                                        \
            uint2 q = H2[(size_t)(R) * 32 + sub];                                \
            float2 f01 = __half22float2(*(const __half2*)&q.x);                  \
            float2 f23 = __half22float2(*(const __half2*)&q.y);                  \
            acc.x += f01.x; acc.y += f01.y;                                      \
            acc.z += f23.x; acc.w += f23.y;                                      \
        }

    for (; ed + 7 < end; ed += 8) {
        int r0 = csr[ed     + half];
        int r1 = csr[ed + 2 + half];
        int r2 = csr[ed + 4 + half];
        int r3 = csr[ed + 6 + half];
        EDGE_ADD(r0); EDGE_ADD(r1); EDGE_ADD(r2); EDGE_ADD(r3);
    }
    #pragma unroll
    for (int s = 0; s < 4; ++s) {          // tail: up to 7 edges
        int idx = ed + 2 * s + half;
        if (idx < end) {
            int r = csr[idx];
            EDGE_ADD(r);
        }
    }
    #undef EDGE_ADD

    acc.x += __shfl_xor(acc.x, 32);
    acc.y += __shfl_xor(acc.y, 32);
    acc.z += __shfl_xor(acc.z, 32);
    acc.w += __shfl_xor(acc.w, 32);

    float di = dinv[node];
    uint2 qh = H2[(size_t)node * 32 + sub];
    float2 h01 = __half22float2(*(const __half2*)&qh.x);
    float2 h23 = __half22float2(*(const __half2*)&qh.y);
    float4 bv = ((const float4*)b)[sub];
    float4 o;
    o.x = fmaxf(fmaf(di, acc.x + h01.x, bv.x), 0.f);
    o.y = fmaxf(fmaf(di, acc.y + h01.y, bv.y), 0.f);
    o.z = fmaxf(fmaf(di, acc.z + h23.x, bv.z), 0.f);
    o.w = fmaxf(fmaf(di, acc.w + h23.y, bv.w), 0.f);
    if (half == 0)
        ((float4*)out)[(size_t)node * 32 + sub] = o;
}

// F=16 gather-aggregate from f16 h': 8 lanes/node (4 x uint2, even/odd halves).
__global__ __launch_bounds__(256) void k_agg16(const __half* __restrict__ Ch, const unsigned short* __restrict__ csr,
                                               const int* __restrict__ offs, const float* __restrict__ dinv,
                                               const float* __restrict__ b, float* __restrict__ out, int n) {
    int t = blockIdx.x * 256 + threadIdx.x;
    int node = t >> 3;
    if (node >= n) return;
    int lane = t & 7;
    int sub  = lane & 3;      // uint2 (4 halves) within the 16-f row
    int half = lane >> 2;
    const uint2* C2 = (const uint2*)Ch;   // row stride = 4 uint2
    int ed = offs[node], end = offs[node + 1];
    float4 acc = make_float4(0.f, 0.f, 0.f, 0.f);

    #define EDGE_ADD16(R)                                                        \
        {                                                                        \
            uint2 q = C2[(size_t)(R) * 4 + sub];                                 \
            float2 f01 = __half22float2(*(const __half2*)&q.x);                  \
            float2 f23 = __half22float2(*(const __half2*)&q.y);                  \
            acc.x += f01.x; acc.y += f01.y;                                      \
            acc.z += f23.x; acc.w += f23.y;                                      \
        }

    for (; ed + 3 < end; ed += 4) {
        int r0 = csr[ed     + half];
        int r1 = csr[ed + 2 + half];
        EDGE_ADD16(r0); EDGE_ADD16(r1);
    }
    #pragma unroll
    for (int s = 0; s < 2; ++s) {          // tail: up to 3 edges
        int idx = ed + 2 * s + half;
        if (idx < end) {
            int r = csr[idx];
            EDGE_ADD16(r);
        }
    }
    #undef EDGE_ADD16

    acc.x += __shfl_xor(acc.x, 4);
    acc.y += __shfl_xor(acc.y, 4);
    acc.z += __shfl_xor(acc.z, 4);
    acc.w += __shfl_xor(acc.w, 4);

    float di = dinv[node];
    uint2 qh = C2[(size_t)node * 4 + sub];
    float2 h01 = __half22float2(*(const __half2*)&qh.x);
    float2 h23 = __half22float2(*(const __half2*)&qh.y);
    float4 bv = ((const float4*)b)[sub];
    float4 o;
    o.x = fmaxf(fmaf(di, acc.x + h01.x, bv.x), 0.f);
    o.y = fmaxf(fmaf(di, acc.y + h01.y, bv.y), 0.f);
    o.z = fmaxf(fmaf(di, acc.z + h23.x, bv.z), 0.f);
    o.w = fmaxf(fmaf(di, acc.w + h23.y, bv.w), 0.f);
    if (half == 0)
        ((float4*)out)[(size_t)node * 4 + sub] = o;
}

extern "C" void kernel_launch(void* const* d_in, const int* in_sizes, int n_in,
                              void* d_out, int out_size, void* d_ws, size_t ws_size,
                              hipStream_t stream) {
    const float* x  = (const float*)d_in[0];
    const int*   ei = (const int*)d_in[1];
    const float* W1 = (const float*)d_in[2];
    const float* b1 = (const float*)d_in[3];
    const float* W2 = (const float*)d_in[4];
    const float* b2 = (const float*)d_in[5];
    const float* W3 = (const float*)d_in[6];
    const float* b3 = (const float*)d_in[7];

    const int n = in_sizes[0] / 128;   // 50000 (< 65536, required by 16-bit CSR)
    const int e = in_sizes[1] / 2;
    const int* row = ei;       // source j
    const int* col = ei + e;   // target i

    unsigned short* csr = (unsigned short*)d_ws;
    __half* Ah  = (__half*)(csr + ((e + 1) & ~1));
    float*  B   = (float*)(Ah + (size_t)n * 128);
    __half* Ch  = (__half*)(B + (size_t)n * 128);
    float* dinv = (float*)(Ch + (size_t)n * 16);
    int*   offs = (int*)(dinv + n);
    int*   cnt  = offs + (n + 1);
    int*   cur  = cnt + n;
    int*   bsum = cur + n;
    float* out  = (float*)d_out;

    const int nb = cdiv(n + 1, 256);
    const int fillBlocks = 256;          // per replica; grid = 8 * 256

    // --- CSR build ---
    k_zero_int<<<cdiv(n, 256), 256, 0, stream>>>(cnt, n);
    k_count   <<<cdiv(e, 256), 256, 0, stream>>>(col, cnt, e);
    k_scanA   <<<nb, 256, 0, stream>>>(cnt, bsum, dinv, n);
    k_scanB   <<<1, 256, 0, stream>>>(bsum, nb);
    k_scanC   <<<nb, 256, 0, stream>>>(cnt, bsum, offs, cur, n);
    k_fill_xcd<<<8 * fillBlocks, 256, 0, stream>>>(row, col, cur, csr, e, n, fillBlocks);

    // --- layer 1 ---
    k_gemm128<<<cdiv(n, 128), 256, 0, stream>>>(x, W1, dinv, Ah, n);
    k_agg128 <<<cdiv(n * 64, 256), 256, 0, stream>>>(Ah, csr, offs, dinv, b1, B, n);
    // --- layer 2 ---
    k_gemm128<<<cdiv(n, 128), 256, 0, stream>>>(B, W2, dinv, Ah, n);
    k_agg128 <<<cdiv(n * 64, 256), 256, 0, stream>>>(Ah, csr, offs, dinv, b2, B, n);
    // --- layer 3 ---
    k_gemm16 <<<cdiv(n, 16), 256, 0, stream>>>(B, W3, dinv, Ch, n);
    k_agg16  <<<cdiv(n * 8, 256), 256, 0, stream>>>(Ch, csr, offs, dinv, b3, out, n);
}